// Round 3
// baseline (201.543 us; speedup 1.0000x reference)
//
#include <hip/hip_runtime.h>
#include <hip/hip_bf16.h>
#include <cstdint>

// ---------------- problem constants (fixed by harness) ----------------
constexpr int CBATCH = 32;    // B
constexpr int CT = 800;       // T frames
constexpr int CD = 512;       // eprojs (K)
constexpr int CV = 1024;      // odim (N)
constexpr int CL = 100;       // max label len
constexpr int CM = CBATCH * CT;   // 25600 GEMM rows
constexpr int CS = 2 * CL + 1;    // 201 extended states
constexpr int CSP = 204;          // padded state count (51 lanes * 4)
constexpr float NEGV = -1e30f;
constexpr float INV_LN2 = 1.4426950408889634f;
constexpr float LN2F = 0.6931471805599453f;

typedef __bf16 bf16x8 __attribute__((ext_vector_type(8)));
typedef float f32x4 __attribute__((ext_vector_type(4)));

// ---------------- helpers ----------------
__device__ inline unsigned short f2bf(float f) {
  union { float f; unsigned u; } v; v.f = f;
  unsigned u = v.u;
  unsigned r = (u + 0x7fffu + ((u >> 16) & 1u)) >> 16;
  return (unsigned short)r;
}

__device__ inline float fexp2(float x) {
#if __has_builtin(__builtin_amdgcn_exp2f)
  return __builtin_amdgcn_exp2f(x);
#else
  return __expf(x * LN2F);
#endif
}
__device__ inline float flog2(float x) {
#if __has_builtin(__builtin_amdgcn_logf)
  return __builtin_amdgcn_logf(x);   // v_log_f32 is log2
#else
  return __logf(x) * INV_LN2;
#endif
}

// log2-domain logaddexp: log2(2^x + 2^y)
__device__ inline float lae2_2(float x, float y) {
  float m = fmaxf(x, y);
  float d = fminf(x, y) - m;           // <= 0
  return m + flog2(1.0f + fexp2(d));
}
// 3-way: log2(2^x + 2^y + 2^z)
__device__ inline float lae2_3(float x, float y, float z) {
  float m = fmaxf(fmaxf(x, y), z);     // v_max3
  float s = fexp2(x - m) + fexp2(y - m) + fexp2(z - m);
  return m + flog2(s);
}

// wave_shr:1 — lane i gets lane i-1's value; lane 0 gets `fill`. Pure VALU (DPP).
__device__ inline float dpp_shr1(float x, float fill) {
  int xi = __builtin_bit_cast(int, x);
  int fi = __builtin_bit_cast(int, fill);
  int r = __builtin_amdgcn_update_dpp(fi, xi, 0x138, 0xF, 0xF, false);
  return __builtin_bit_cast(float, r);
}

// ---------------- 1. fp32 -> bf16 convert ----------------
__global__ void cvt_kernel(const float* __restrict__ in, unsigned short* __restrict__ out, int n4) {
  int i = blockIdx.x * blockDim.x + threadIdx.x;
  if (i < n4) {
    float4 v = reinterpret_cast<const float4*>(in)[i];
    ushort4 o;
    o.x = f2bf(v.x); o.y = f2bf(v.y); o.z = f2bf(v.z); o.w = f2bf(v.w);
    reinterpret_cast<ushort4*>(out)[i] = o;
  }
}

// ---------------- 2. bf16 MFMA GEMM: C[M,V] = A[M,D] * Bt[V,D]^T + bias ----------------
// m97 structure: linear [128][64] LDS tiles staged via global_load_lds width=16.
constexpr int GBK = 64;    // K-tile

__device__ inline void gload_lds16(const void* g, void* l) {
  __builtin_amdgcn_global_load_lds(
      (const __attribute__((address_space(1))) unsigned int*)g,
      (__attribute__((address_space(3))) unsigned int*)l, 16, 0, 0);
}

__global__ __launch_bounds__(256, 2) void gemm_kernel(
    const unsigned short* __restrict__ A,   // [CM, CD] bf16 bits
    const unsigned short* __restrict__ Bt,  // [CV, CD] bf16 bits
    const float* __restrict__ bias,         // [CV]
    float* __restrict__ C)                  // [CM, CV] fp32
{
  __shared__ __align__(16) unsigned short As[128 * GBK];  // 16 KB, linear
  __shared__ __align__(16) unsigned short Bs[128 * GBK];
  const int tid = threadIdx.x;
  const int lane = tid & 63;
  const int wave = tid >> 6;          // 4 waves, 2x2 of 64x64
  const int wr = wave >> 1, wc = wave & 1;
  const int bm = blockIdx.x, bn = blockIdx.y;

  f32x4 acc[4][4] = {};

  for (int k0 = 0; k0 < CD; k0 += GBK) {
    // stage A,B tiles: 1024 16B-chunks per tile, 4 per thread.
#pragma unroll
    for (int i = 0; i < 4; ++i) {
      int c = tid + 256 * i;
      int row = c >> 3, col = (c & 7) * 8;
      gload_lds16(&A[(size_t)(bm * 128 + row) * CD + k0 + col], &As[c * 8]);
      gload_lds16(&Bt[(size_t)(bn * 128 + row) * CD + k0 + col], &Bs[c * 8]);
    }
    __syncthreads();   // compiler drains vmcnt before s_barrier
#pragma unroll
    for (int kk = 0; kk < 2; ++kk) {
      bf16x8 af[4], bfr[4];
#pragma unroll
      for (int m = 0; m < 4; ++m)
        af[m] = *reinterpret_cast<const bf16x8*>(
            &As[(wr * 64 + m * 16 + (lane & 15)) * GBK + kk * 32 + (lane >> 4) * 8]);
#pragma unroll
      for (int n = 0; n < 4; ++n)
        bfr[n] = *reinterpret_cast<const bf16x8*>(
            &Bs[(wc * 64 + n * 16 + (lane & 15)) * GBK + kk * 32 + (lane >> 4) * 8]);
#pragma unroll
      for (int m = 0; m < 4; ++m)
#pragma unroll
        for (int n = 0; n < 4; ++n)
          acc[m][n] = __builtin_amdgcn_mfma_f32_16x16x32_bf16(af[m], bfr[n], acc[m][n], 0, 0, 0);
    }
    __syncthreads();
  }

  // epilogue: C layout col=lane&15, row=(lane>>4)*4+reg  [verified m89/m91]
  float bv[4];
#pragma unroll
  for (int n = 0; n < 4; ++n)
    bv[n] = bias[bn * 128 + wc * 64 + n * 16 + (lane & 15)];
#pragma unroll
  for (int m = 0; m < 4; ++m) {
    int rbase = bm * 128 + wr * 64 + m * 16 + (lane >> 4) * 4;
#pragma unroll
    for (int n = 0; n < 4; ++n) {
      int col = bn * 128 + wc * 64 + n * 16 + (lane & 15);
#pragma unroll
      for (int r = 0; r < 4; ++r)
        C[(size_t)(rbase + r) * CV + col] = acc[m][n][r] + bv[n];
    }
  }
}

// ---------------- 3. fused row log-sum-exp + extended-label gather ----------------
// one wave per (b,t) row; lp output pre-scaled to log2 domain.
__global__ void lse_gather_kernel(const float* __restrict__ C, const int* __restrict__ labels,
                                  float* __restrict__ lpg) {
  const int wave = threadIdx.x >> 6, lane = threadIdx.x & 63;
  const int row = blockIdx.x * 4 + wave;   // bt
  const int b = row / CT;
  const float* p = C + (size_t)row * CV;
  float4 v[4];
#pragma unroll
  for (int i = 0; i < 4; ++i) v[i] = reinterpret_cast<const float4*>(p)[lane + 64 * i];
  float m = v[0].x;
#pragma unroll
  for (int i = 0; i < 4; ++i) {
    m = fmaxf(m, v[i].x); m = fmaxf(m, v[i].y);
    m = fmaxf(m, v[i].z); m = fmaxf(m, v[i].w);
  }
#pragma unroll
  for (int off = 32; off >= 1; off >>= 1) m = fmaxf(m, __shfl_xor(m, off));
  float s = 0.f;
#pragma unroll
  for (int i = 0; i < 4; ++i) {
    s += __expf(v[i].x - m); s += __expf(v[i].y - m);
    s += __expf(v[i].z - m); s += __expf(v[i].w - m);
  }
#pragma unroll
  for (int off = 32; off >= 1; off >>= 1) s += __shfl_xor(s, off);
  const float l = m + __logf(s);           // natural-log lse, all lanes have it

  if (lane < CSP / 4) {                    // 51 active lanes gather
    const int* lab = labels + b * CL;
    const int s0 = lane * 4;
    float vals[4];
#pragma unroll
    for (int j = 0; j < 4; ++j) {
      int st = s0 + j;
      if (st >= CS) { vals[j] = NEGV; continue; }
      int e = (st & 1) ? lab[st >> 1] : 0;
      vals[j] = (p[e] - l) * INV_LN2;      // log2 domain
    }
    float4 o; o.x = vals[0]; o.y = vals[1]; o.z = vals[2]; o.w = vals[3];
    reinterpret_cast<float4*>(lpg + (size_t)row * CSP)[lane] = o;
  }
}

// ---------------- 4. CTC alpha recursion (log2 domain): one wave per batch ----------------
// __launch_bounds__(64, 1): only 32 waves exist chip-wide; let the register
// allocator keep the 16-deep float4 prefetch ring resident (round-2 build had
// VGPR=44 -> ring sunk -> full load latency per step).
__global__ __launch_bounds__(64, 1) void ctc_kernel(
    const float* __restrict__ lpg, const int* __restrict__ labels,
    const int* __restrict__ ilens, const int* __restrict__ llens,
    float* __restrict__ out) {
  const int b = blockIdx.x;
  const int lane = threadIdx.x;
  const int ilen = ilens[b];
  const int ll = llens[b];
  const int* lab = labels + b * CL;
  const int s0 = lane * 4;

  // skip-transition allow flags: only odd states (j=1,3) can be allowed
  bool al1 = false, al3 = false;
  if (lane < CSP / 4) {
    int s1 = s0 + 1;
    if (s1 >= 3 && s1 < CS) al1 = (lab[s1 >> 1] != lab[(s1 >> 1) - 1]);
    int s3 = s0 + 3;
    if (s3 < CS) al3 = (lab[s3 >> 1] != lab[(s3 >> 1) - 1]);
  }

  const float* base = lpg + (size_t)b * CT * CSP;

  // init from t=0 row (log2 domain). Unguarded 64-lane loads overrun the
  // 816B row into the next row / pad — harmless, values discarded.
  float4 r0 = reinterpret_cast<const float4*>(base)[lane];
  float a[4];
  a[0] = (lane == 0) ? r0.x : NEGV;
  a[1] = (lane == 0 && ll > 0) ? r0.y : NEGV;
  a[2] = NEGV; a[3] = NEGV;

  // 16-deep register prefetch ring; pf[u] holds row (tb+u) at group start
  float4 pf[16];
#pragma unroll
  for (int u = 0; u < 16; ++u)
    pf[u] = reinterpret_cast<const float4*>(base + (size_t)(1 + u) * CSP)[lane];

  // t runs 1..800 exactly (50 groups of 16); t=800 update is masked off by
  // active=(t<ilen) since ilen<=800.
  for (int tb = 1; tb < CT + 1; tb += 16) {
#pragma unroll
    for (int u = 0; u < 16; ++u) {
      const int t = tb + u;
      float4 lp = pf[u];
      pf[u] = reinterpret_cast<const float4*>(base + (size_t)(t + 16) * CSP)[lane];
      float na3 = dpp_shr1(a[3], NEGV);          // state s0-1 from prev lane
      // j=0 (blank): paths {s, s-1}
      float c0 = lae2_2(a[0], na3);
      // j=1 (label): paths {s, s-1, s-2?}; s-1=a[0], s-2=na3
      float c1 = lae2_3(a[1], a[0], al1 ? na3 : NEGV);
      // j=2 (blank)
      float c2 = lae2_2(a[2], a[1]);
      // j=3 (label): s-1=a[2], s-2=a[1]
      float c3 = lae2_3(a[3], a[2], al3 ? a[1] : NEGV);
      if (t < ilen) {
        a[0] = c0 + lp.x; a[1] = c1 + lp.y;
        a[2] = c2 + lp.z; a[3] = c3 + lp.w;
      }
    }
  }

  __shared__ float sal[CSP];
  if (lane < CSP / 4) {
#pragma unroll
    for (int j = 0; j < 4; ++j) sal[s0 + j] = a[j];
  }
  __syncthreads();
  if (lane == 0) {
    float last = sal[2 * ll];
    float prev = (ll > 0) ? sal[2 * ll - 1] : NEGV;
    float v = lae2_2(last, prev);                // log2 domain
    atomicAdd(out, -v * (LN2F / CBATCH));        // back to natural log
  }
}

// ---------------- launch ----------------
extern "C" void kernel_launch(void* const* d_in, const int* in_sizes, int n_in,
                              void* d_out, int out_size, void* d_ws, size_t ws_size,
                              hipStream_t stream) {
  const float* hpad = (const float*)d_in[0];
  const float* W    = (const float*)d_in[1];
  const float* bias = (const float*)d_in[2];
  const int* labels = (const int*)d_in[3];
  const int* ilens  = (const int*)d_in[4];
  const int* llens  = (const int*)d_in[5];
  float* out = (float*)d_out;

  char* ws = (char*)d_ws;
  size_t off = 0;
  auto alloc = [&](size_t bytes) -> void* {
    void* p = ws + off;
    off = (off + bytes + 255) & ~(size_t)255;
    return p;
  };
  unsigned short* Abf = (unsigned short*)alloc((size_t)CM * CD * 2);        // 26.2 MB
  unsigned short* Wbf = (unsigned short*)alloc((size_t)CV * CD * 2);        //  1.0 MB
  float* logits = (float*)alloc((size_t)CM * CV * 4);                       // 104.9 MB
  float* lpg    = (float*)alloc((size_t)(CM + 64) * CSP * 4);               // 21.0 MB (+pad for prefetch overrun)

  hipMemsetAsync(d_out, 0, sizeof(float), stream);

  cvt_kernel<<<(CM * CD / 4 + 255) / 256, 256, 0, stream>>>(hpad, Abf, CM * CD / 4);
  cvt_kernel<<<(CV * CD / 4 + 255) / 256, 256, 0, stream>>>(W, Wbf, CV * CD / 4);
  gemm_kernel<<<dim3(CM / 128, CV / 128), 256, 0, stream>>>(Abf, Wbf, bias, logits);
  lse_gather_kernel<<<CM / 4, 256, 0, stream>>>(logits, labels, lpg);
  ctc_kernel<<<CBATCH, 64, 0, stream>>>(lpg, labels, ilens, llens, out);
}

// Round 4
// 182.421 us; speedup vs baseline: 1.1048x; 1.1048x over previous
//
#include <hip/hip_runtime.h>
#include <hip/hip_bf16.h>
#include <cstdint>

// ---------------- problem constants (fixed by harness) ----------------
constexpr int CBATCH = 32;    // B
constexpr int CT = 800;       // T frames
constexpr int CD = 512;       // eprojs (K)
constexpr int CV = 1024;      // odim (N)
constexpr int CL = 100;       // max label len
constexpr int CM = CBATCH * CT;   // 25600 GEMM rows
constexpr int CS = 2 * CL + 1;    // 201 extended states
constexpr int CSP = 204;          // padded state count (51 lanes * 4)
constexpr float NEGV = -1e30f;
constexpr float INV_LN2 = 1.4426950408889634f;
constexpr float LN2F = 0.6931471805599453f;

typedef __bf16 bf16x8 __attribute__((ext_vector_type(8)));
typedef float f32x4 __attribute__((ext_vector_type(4)));
typedef unsigned short ushort8 __attribute__((ext_vector_type(8)));

// ---------------- helpers ----------------
__device__ inline unsigned short f2bf(float f) {
  union { float f; unsigned u; } v; v.f = f;
  unsigned u = v.u;
  unsigned r = (u + 0x7fffu + ((u >> 16) & 1u)) >> 16;
  return (unsigned short)r;
}
__device__ inline float bf2f(unsigned short u) {
  unsigned x = (unsigned)u << 16;
  return __builtin_bit_cast(float, x);
}

__device__ inline float fexp2(float x) { return __builtin_amdgcn_exp2f(x); }
__device__ inline float flog2(float x) { return __builtin_amdgcn_logf(x); }

// log2-domain logaddexp: log2(2^x + 2^y)
__device__ inline float lae2_2(float x, float y) {
  float m = fmaxf(x, y);
  float d = fminf(x, y) - m;           // <= 0
  return m + flog2(1.0f + fexp2(d));
}
// 3-way: log2(2^x + 2^y + 2^z)
__device__ inline float lae2_3(float x, float y, float z) {
  float m = fmaxf(fmaxf(x, y), z);     // v_max3
  float s = fexp2(x - m) + fexp2(y - m) + fexp2(z - m);
  return m + flog2(s);
}

// wave_shr:1 — lane i gets lane i-1's value; lane 0 gets `fill`. Pure VALU (DPP).
__device__ inline float dpp_shr1(float x, float fill) {
  int xi = __builtin_bit_cast(int, x);
  int fi = __builtin_bit_cast(int, fill);
  int r = __builtin_amdgcn_update_dpp(fi, xi, 0x138, 0xF, 0xF, false);
  return __builtin_bit_cast(float, r);
}

// ---------------- 1. fp32 -> bf16 convert ----------------
__global__ void cvt_kernel(const float* __restrict__ in, unsigned short* __restrict__ out, int n4) {
  int i = blockIdx.x * blockDim.x + threadIdx.x;
  if (i < n4) {
    float4 v = reinterpret_cast<const float4*>(in)[i];
    ushort4 o;
    o.x = f2bf(v.x); o.y = f2bf(v.y); o.z = f2bf(v.z); o.w = f2bf(v.w);
    reinterpret_cast<ushort4*>(out)[i] = o;
  }
}

// ---------------- 2. bf16 MFMA GEMM: C[M,V] = A[M,D] * Bt[V,D]^T + bias (bf16 out) ----
constexpr int GBK = 64;    // K-tile

__device__ inline void gload_lds16(const void* g, void* l) {
  __builtin_amdgcn_global_load_lds(
      (const __attribute__((address_space(1))) unsigned int*)g,
      (__attribute__((address_space(3))) unsigned int*)l, 16, 0, 0);
}

__global__ __launch_bounds__(256, 2) void gemm_kernel(
    const unsigned short* __restrict__ A,   // [CM, CD] bf16 bits
    const unsigned short* __restrict__ Bt,  // [CV, CD] bf16 bits
    const float* __restrict__ bias,         // [CV]
    unsigned short* __restrict__ C)         // [CM, CV] bf16 bits
{
  __shared__ __align__(16) unsigned short As[128 * GBK];  // 16 KB, linear
  __shared__ __align__(16) unsigned short Bs[128 * GBK];
  const int tid = threadIdx.x;
  const int lane = tid & 63;
  const int wave = tid >> 6;          // 4 waves, 2x2 of 64x64
  const int wr = wave >> 1, wc = wave & 1;
  const int bm = blockIdx.x, bn = blockIdx.y;

  f32x4 acc[4][4] = {};

  for (int k0 = 0; k0 < CD; k0 += GBK) {
#pragma unroll
    for (int i = 0; i < 4; ++i) {
      int c = tid + 256 * i;
      int row = c >> 3, col = (c & 7) * 8;
      gload_lds16(&A[(size_t)(bm * 128 + row) * CD + k0 + col], &As[c * 8]);
      gload_lds16(&Bt[(size_t)(bn * 128 + row) * CD + k0 + col], &Bs[c * 8]);
    }
    __syncthreads();
#pragma unroll
    for (int kk = 0; kk < 2; ++kk) {
      bf16x8 af[4], bfr[4];
#pragma unroll
      for (int m = 0; m < 4; ++m)
        af[m] = *reinterpret_cast<const bf16x8*>(
            &As[(wr * 64 + m * 16 + (lane & 15)) * GBK + kk * 32 + (lane >> 4) * 8]);
#pragma unroll
      for (int n = 0; n < 4; ++n)
        bfr[n] = *reinterpret_cast<const bf16x8*>(
            &Bs[(wc * 64 + n * 16 + (lane & 15)) * GBK + kk * 32 + (lane >> 4) * 8]);
#pragma unroll
      for (int m = 0; m < 4; ++m)
#pragma unroll
        for (int n = 0; n < 4; ++n)
          acc[m][n] = __builtin_amdgcn_mfma_f32_16x16x32_bf16(af[m], bfr[n], acc[m][n], 0, 0, 0);
    }
    __syncthreads();
  }

  // epilogue: C layout col=lane&15, row=(lane>>4)*4+reg  [verified m89/m91]
  float bv[4];
#pragma unroll
  for (int n = 0; n < 4; ++n)
    bv[n] = bias[bn * 128 + wc * 64 + n * 16 + (lane & 15)];
#pragma unroll
  for (int m = 0; m < 4; ++m) {
    int rbase = bm * 128 + wr * 64 + m * 16 + (lane >> 4) * 4;
#pragma unroll
    for (int n = 0; n < 4; ++n) {
      int col = bn * 128 + wc * 64 + n * 16 + (lane & 15);
#pragma unroll
      for (int r = 0; r < 4; ++r)
        C[(size_t)(rbase + r) * CV + col] = f2bf(acc[m][n][r] + bv[n]);
    }
  }
}

// ---------------- 3. fused row log-sum-exp + extended-label gather (bf16 logits) ----
__global__ void lse_gather_kernel(const unsigned short* __restrict__ C,
                                  const int* __restrict__ labels,
                                  float* __restrict__ lpg) {
  const int wave = threadIdx.x >> 6, lane = threadIdx.x & 63;
  const int row = blockIdx.x * 4 + wave;   // bt
  const int b = row / CT;
  const unsigned short* p = C + (size_t)row * CV;
  // 16 bf16 per lane (two 16B chunks), lane-contiguous -> coalesced
  ushort8 v0 = reinterpret_cast<const ushort8*>(p)[lane * 2];
  ushort8 v1 = reinterpret_cast<const ushort8*>(p)[lane * 2 + 1];
  float f[16];
#pragma unroll
  for (int i = 0; i < 8; ++i) { f[i] = bf2f(v0[i]); f[8 + i] = bf2f(v1[i]); }
  float m = f[0];
#pragma unroll
  for (int i = 1; i < 16; ++i) m = fmaxf(m, f[i]);
#pragma unroll
  for (int off = 32; off >= 1; off >>= 1) m = fmaxf(m, __shfl_xor(m, off));
  float s = 0.f;
#pragma unroll
  for (int i = 0; i < 16; ++i) s += __expf(f[i] - m);
#pragma unroll
  for (int off = 32; off >= 1; off >>= 1) s += __shfl_xor(s, off);
  const float l = m + __logf(s);           // natural-log lse, all lanes have it

  if (lane < CSP / 4) {                    // 51 active lanes gather
    const int* lab = labels + b * CL;
    const int s0 = lane * 4;
    float vals[4];
#pragma unroll
    for (int j = 0; j < 4; ++j) {
      int st = s0 + j;
      if (st >= CS) { vals[j] = NEGV; continue; }
      int e = (st & 1) ? lab[st >> 1] : 0;
      vals[j] = (bf2f(p[e]) - l) * INV_LN2;   // log2 domain
    }
    float4 o; o.x = vals[0]; o.y = vals[1]; o.z = vals[2]; o.w = vals[3];
    reinterpret_cast<float4*>(lpg + (size_t)row * CSP)[lane] = o;
  }
}

// ---------------- 4. CTC alpha recursion (log2 domain): one wave per batch ----------------
// Round-3 lesson: LLVM sinks/remats plain loads to their uses (const restrict,
// no aliasing stores), destroying any source-level prefetch ring (VGPR=48).
// Fix: volatile-asm global_load_dwordx4 ring (depth 32) the compiler cannot
// move, with explicit s_waitcnt vmcnt(31) + sched_barrier(0) per step.
constexpr int PFD = 32;                 // prefetch depth (ring slots)
constexpr int ROWB = CSP * 4;           // 816 bytes per row

__global__ __launch_bounds__(64, 1) void ctc_kernel(
    const float* __restrict__ lpg, const int* __restrict__ labels,
    const int* __restrict__ ilens, const int* __restrict__ llens,
    float* __restrict__ out) {
  const int b = blockIdx.x;
  const int lane = threadIdx.x;
  const int ilen = ilens[b];
  const int ll = llens[b];
  const int* lab = labels + b * CL;
  const int s0 = lane * 4;

  // skip-transition allow flags: only odd states (j=1,3) can be allowed
  bool al1 = false, al3 = false;
  if (lane < CSP / 4) {
    int s1 = s0 + 1;
    if (s1 >= 3 && s1 < CS) al1 = (lab[s1 >> 1] != lab[(s1 >> 1) - 1]);
    int s3 = s0 + 3;
    if (s3 < CS) al3 = (lab[s3 >> 1] != lab[(s3 >> 1) - 1]);
  }

  const float* base = lpg + (size_t)b * CT * CSP;

  // init from t=0 row (log2 domain)
  f32x4 r0 = reinterpret_cast<const f32x4*>(base)[lane];
  float a[4];
  a[0] = (lane == 0) ? r0[0] : NEGV;
  a[1] = (lane == 0 && ll > 0) ? r0[1] : NEGV;
  a[2] = NEGV; a[3] = NEGV;

  // prologue: fill the 32-deep ring with rows 1..32 (volatile asm, saddr form)
  f32x4 pf[PFD];
#pragma unroll
  for (int u = 0; u < PFD; ++u) {
    int voff = (1 + u) * ROWB + lane * 16;
    asm volatile("global_load_dwordx4 %0, %1, %2"
                 : "=&v"(pf[u]) : "v"(voff), "s"(base));
  }

  // t runs 1..800 (25 groups of 32); t=800 update masked by active=(t<ilen).
  for (int tb = 1; tb < CT + 1; tb += PFD) {
#pragma unroll
    for (int u = 0; u < PFD; ++u) {
      const int t = tb + u;
      // ring slot u's load (issued PFD steps ago) is the PFD-th newest:
      // wait until <= PFD-1 outstanding -> it has landed.
      asm volatile("s_waitcnt vmcnt(31)" ::: "memory");
      __builtin_amdgcn_sched_barrier(0);
      f32x4 lp = pf[u];
      int voff = (t + PFD) * ROWB + lane * 16;
      asm volatile("global_load_dwordx4 %0, %1, %2"
                   : "=&v"(pf[u]) : "v"(voff), "s"(base));
      float na3 = dpp_shr1(a[3], NEGV);          // state s0-1 from prev lane
      float c0 = lae2_2(a[0], na3);                          // blank
      float c1 = lae2_3(a[1], a[0], al1 ? na3 : NEGV);       // label
      float c2 = lae2_2(a[2], a[1]);                         // blank
      float c3 = lae2_3(a[3], a[2], al3 ? a[1] : NEGV);      // label
      if (t < ilen) {
        a[0] = c0 + lp[0]; a[1] = c1 + lp[1];
        a[2] = c2 + lp[2]; a[3] = c3 + lp[3];
      }
    }
  }

  __shared__ float sal[CSP];
  if (lane < CSP / 4) {
#pragma unroll
    for (int j = 0; j < 4; ++j) sal[s0 + j] = a[j];
  }
  __syncthreads();
  if (lane == 0) {
    float last = sal[2 * ll];
    float prev = (ll > 0) ? sal[2 * ll - 1] : NEGV;
    float v = lae2_2(last, prev);                // log2 domain
    atomicAdd(out, -v * (LN2F / CBATCH));        // back to natural log
  }
}

// ---------------- launch ----------------
extern "C" void kernel_launch(void* const* d_in, const int* in_sizes, int n_in,
                              void* d_out, int out_size, void* d_ws, size_t ws_size,
                              hipStream_t stream) {
  const float* hpad = (const float*)d_in[0];
  const float* W    = (const float*)d_in[1];
  const float* bias = (const float*)d_in[2];
  const int* labels = (const int*)d_in[3];
  const int* ilens  = (const int*)d_in[4];
  const int* llens  = (const int*)d_in[5];
  float* out = (float*)d_out;

  char* ws = (char*)d_ws;
  size_t off = 0;
  auto alloc = [&](size_t bytes) -> void* {
    void* p = ws + off;
    off = (off + bytes + 255) & ~(size_t)255;
    return p;
  };
  unsigned short* Abf = (unsigned short*)alloc((size_t)CM * CD * 2);        // 26.2 MB
  unsigned short* Wbf = (unsigned short*)alloc((size_t)CV * CD * 2);        //  1.0 MB
  unsigned short* logits = (unsigned short*)alloc((size_t)CM * CV * 2);     // 52.4 MB bf16
  float* lpg    = (float*)alloc((size_t)(CM + 64) * CSP * 4);               // 21.0 MB (+pad for prefetch overrun)

  hipMemsetAsync(d_out, 0, sizeof(float), stream);

  cvt_kernel<<<(CM * CD / 4 + 255) / 256, 256, 0, stream>>>(hpad, Abf, CM * CD / 4);
  cvt_kernel<<<(CV * CD / 4 + 255) / 256, 256, 0, stream>>>(W, Wbf, CV * CD / 4);
  gemm_kernel<<<dim3(CM / 128, CV / 128), 256, 0, stream>>>(Abf, Wbf, bias, logits);
  lse_gather_kernel<<<CM / 4, 256, 0, stream>>>(logits, labels, lpg);
  ctc_kernel<<<CBATCH, 64, 0, stream>>>(lpg, labels, ilens, llens, out);
}

// Round 5
// 178.376 us; speedup vs baseline: 1.1299x; 1.0227x over previous
//
#include <hip/hip_runtime.h>
#include <hip/hip_bf16.h>
#include <cstdint>

// ---------------- problem constants (fixed by harness) ----------------
constexpr int CBATCH = 32;    // B
constexpr int CT = 800;       // T frames
constexpr int CD = 512;       // eprojs (K)
constexpr int CV = 1024;      // odim (N)
constexpr int CL = 100;       // max label len
constexpr int CM = CBATCH * CT;   // 25600 GEMM rows
constexpr int CS = 2 * CL + 1;    // 201 extended states
constexpr int CSP = 204;          // padded state count (51 lanes * 4)
constexpr float NEGV = -1e30f;
constexpr float INV_LN2 = 1.4426950408889634f;
constexpr float LN2F = 0.6931471805599453f;

typedef __bf16 bf16x8 __attribute__((ext_vector_type(8)));
typedef float f32x4 __attribute__((ext_vector_type(4)));
typedef unsigned short ushort8 __attribute__((ext_vector_type(8)));

// ---------------- helpers ----------------
__device__ inline unsigned short f2bf(float f) {
  union { float f; unsigned u; } v; v.f = f;
  unsigned u = v.u;
  unsigned r = (u + 0x7fffu + ((u >> 16) & 1u)) >> 16;
  return (unsigned short)r;
}
__device__ inline float bf2f(unsigned short u) {
  unsigned x = (unsigned)u << 16;
  return __builtin_bit_cast(float, x);
}

__device__ inline float fexp2(float x) { return __builtin_amdgcn_exp2f(x); }
__device__ inline float flog2(float x) { return __builtin_amdgcn_logf(x); }

// log2-domain logaddexp: log2(2^x + 2^y)
__device__ inline float lae2_2(float x, float y) {
  float m = fmaxf(x, y);
  float d = fminf(x, y) - m;           // <= 0
  return m + flog2(1.0f + fexp2(d));
}
// 3-way: log2(2^x + 2^y + 2^z)
__device__ inline float lae2_3(float x, float y, float z) {
  float m = fmaxf(fmaxf(x, y), z);     // v_max3
  float s = fexp2(x - m) + fexp2(y - m) + fexp2(z - m);
  return m + flog2(s);
}

// wave_shr:1 — lane i gets lane i-1's value; lane 0 gets `fill`. Pure VALU (DPP).
__device__ inline float dpp_shr1(float x, float fill) {
  int xi = __builtin_bit_cast(int, x);
  int fi = __builtin_bit_cast(int, fill);
  int r = __builtin_amdgcn_update_dpp(fi, xi, 0x138, 0xF, 0xF, false);
  return __builtin_bit_cast(float, r);
}

// ---------------- 1. fp32 -> bf16 convert ----------------
__global__ void cvt_kernel(const float* __restrict__ in, unsigned short* __restrict__ out, int n4) {
  int i = blockIdx.x * blockDim.x + threadIdx.x;
  if (i < n4) {
    float4 v = reinterpret_cast<const float4*>(in)[i];
    ushort4 o;
    o.x = f2bf(v.x); o.y = f2bf(v.y); o.z = f2bf(v.z); o.w = f2bf(v.w);
    reinterpret_cast<ushort4*>(out)[i] = o;
  }
}

// ---------------- 2. bf16 MFMA GEMM: C[M,V] = A[M,D] * Bt[V,D]^T + bias (bf16 out) ----
constexpr int GBK = 64;    // K-tile

__device__ inline void gload_lds16(const void* g, void* l) {
  __builtin_amdgcn_global_load_lds(
      (const __attribute__((address_space(1))) unsigned int*)g,
      (__attribute__((address_space(3))) unsigned int*)l, 16, 0, 0);
}

__global__ __launch_bounds__(256, 2) void gemm_kernel(
    const unsigned short* __restrict__ A,   // [CM, CD] bf16 bits
    const unsigned short* __restrict__ Bt,  // [CV, CD] bf16 bits
    const float* __restrict__ bias,         // [CV]
    unsigned short* __restrict__ C)         // [CM, CV] bf16 bits
{
  __shared__ __align__(16) unsigned short As[128 * GBK];  // 16 KB, linear
  __shared__ __align__(16) unsigned short Bs[128 * GBK];
  const int tid = threadIdx.x;
  const int lane = tid & 63;
  const int wave = tid >> 6;          // 4 waves, 2x2 of 64x64
  const int wr = wave >> 1, wc = wave & 1;
  const int bm = blockIdx.x, bn = blockIdx.y;

  f32x4 acc[4][4] = {};

  for (int k0 = 0; k0 < CD; k0 += GBK) {
#pragma unroll
    for (int i = 0; i < 4; ++i) {
      int c = tid + 256 * i;
      int row = c >> 3, col = (c & 7) * 8;
      gload_lds16(&A[(size_t)(bm * 128 + row) * CD + k0 + col], &As[c * 8]);
      gload_lds16(&Bt[(size_t)(bn * 128 + row) * CD + k0 + col], &Bs[c * 8]);
    }
    __syncthreads();
#pragma unroll
    for (int kk = 0; kk < 2; ++kk) {
      bf16x8 af[4], bfr[4];
#pragma unroll
      for (int m = 0; m < 4; ++m)
        af[m] = *reinterpret_cast<const bf16x8*>(
            &As[(wr * 64 + m * 16 + (lane & 15)) * GBK + kk * 32 + (lane >> 4) * 8]);
#pragma unroll
      for (int n = 0; n < 4; ++n)
        bfr[n] = *reinterpret_cast<const bf16x8*>(
            &Bs[(wc * 64 + n * 16 + (lane & 15)) * GBK + kk * 32 + (lane >> 4) * 8]);
#pragma unroll
      for (int m = 0; m < 4; ++m)
#pragma unroll
        for (int n = 0; n < 4; ++n)
          acc[m][n] = __builtin_amdgcn_mfma_f32_16x16x32_bf16(af[m], bfr[n], acc[m][n], 0, 0, 0);
    }
    __syncthreads();
  }

  // epilogue: C layout col=lane&15, row=(lane>>4)*4+reg  [verified m89/m91]
  float bv[4];
#pragma unroll
  for (int n = 0; n < 4; ++n)
    bv[n] = bias[bn * 128 + wc * 64 + n * 16 + (lane & 15)];
#pragma unroll
  for (int m = 0; m < 4; ++m) {
    int rbase = bm * 128 + wr * 64 + m * 16 + (lane >> 4) * 4;
#pragma unroll
    for (int n = 0; n < 4; ++n) {
      int col = bn * 128 + wc * 64 + n * 16 + (lane & 15);
#pragma unroll
      for (int r = 0; r < 4; ++r)
        C[(size_t)(rbase + r) * CV + col] = f2bf(acc[m][n][r] + bv[n]);
    }
  }
}

// ---------------- 3. fused row log-sum-exp + extended-label gather (bf16 logits) ----
__global__ void lse_gather_kernel(const unsigned short* __restrict__ C,
                                  const int* __restrict__ labels,
                                  float* __restrict__ lpg) {
  const int wave = threadIdx.x >> 6, lane = threadIdx.x & 63;
  const int row = blockIdx.x * 4 + wave;   // bt
  const int b = row / CT;
  const unsigned short* p = C + (size_t)row * CV;
  // 16 bf16 per lane (two 16B chunks), lane-contiguous -> coalesced
  ushort8 v0 = reinterpret_cast<const ushort8*>(p)[lane * 2];
  ushort8 v1 = reinterpret_cast<const ushort8*>(p)[lane * 2 + 1];
  float f[16];
#pragma unroll
  for (int i = 0; i < 8; ++i) { f[i] = bf2f(v0[i]); f[8 + i] = bf2f(v1[i]); }
  float m = f[0];
#pragma unroll
  for (int i = 1; i < 16; ++i) m = fmaxf(m, f[i]);
#pragma unroll
  for (int off = 32; off >= 1; off >>= 1) m = fmaxf(m, __shfl_xor(m, off));
  float s = 0.f;
#pragma unroll
  for (int i = 0; i < 16; ++i) s += __expf(f[i] - m);
#pragma unroll
  for (int off = 32; off >= 1; off >>= 1) s += __shfl_xor(s, off);
  const float l = m + __logf(s);           // natural-log lse, all lanes have it

  if (lane < CSP / 4) {                    // 51 active lanes gather
    const int* lab = labels + b * CL;
    const int s0 = lane * 4;
    float vals[4];
#pragma unroll
    for (int j = 0; j < 4; ++j) {
      int st = s0 + j;
      if (st >= CS) { vals[j] = NEGV; continue; }
      int e = (st & 1) ? lab[st >> 1] : 0;
      vals[j] = (bf2f(p[e]) - l) * INV_LN2;   // log2 domain
    }
    float4 o; o.x = vals[0]; o.y = vals[1]; o.z = vals[2]; o.w = vals[3];
    reinterpret_cast<float4*>(lpg + (size_t)row * CSP)[lane] = o;
  }
}

// ---------------- 4. CTC alpha recursion (log2 domain): one wave per batch ----------------
// Round-4 lesson: an ARRAY-based asm ring gets demoted (VGPR=76 < 128 needed;
// spill waits drain the prefetch queue). Fix: 16 individually-NAMED f32x4 ring
// slots, each its own volatile asm load; s_waitcnt vmcnt(15)+sched_barrier(0)
// before consuming a slot (rule #18). Nothing indexable -> nothing demotable.
constexpr int ROWB = CSP * 4;           // 816 bytes per row

__global__ __launch_bounds__(64, 1) void ctc_kernel(
    const float* __restrict__ lpg, const int* __restrict__ labels,
    const int* __restrict__ ilens, const int* __restrict__ llens,
    float* __restrict__ out) {
  const int b = blockIdx.x;
  const int lane = threadIdx.x;
  const int ilen = ilens[b];
  const int ll = llens[b];
  const int* lab = labels + b * CL;
  const int s0 = lane * 4;

  // skip-transition allow flags: only odd states (j=1,3) can be allowed
  bool al1 = false, al3 = false;
  if (lane < CSP / 4) {
    int s1 = s0 + 1;
    if (s1 >= 3 && s1 < CS) al1 = (lab[s1 >> 1] != lab[(s1 >> 1) - 1]);
    int s3 = s0 + 3;
    if (s3 < CS) al3 = (lab[s3 >> 1] != lab[(s3 >> 1) - 1]);
  }

  const float* base = lpg + (size_t)b * CT * CSP;

  // init from t=0 row (log2 domain)
  f32x4 r0 = reinterpret_cast<const f32x4*>(base)[lane];
  float a0, a1, a2, a3;
  a0 = (lane == 0) ? r0[0] : NEGV;
  a1 = (lane == 0 && ll > 0) ? r0[1] : NEGV;
  a2 = NEGV; a3 = NEGV;

#define CTC_LOAD(P, ROW)                                                  \
  { int voff_ = (ROW) * ROWB + lane * 16;                                 \
    asm volatile("global_load_dwordx4 %0, %1, %2"                         \
                 : "=&v"(P) : "v"(voff_), "s"(base)); }

  // prologue: fill 16 named slots with rows 1..16 (16 outstanding)
  f32x4 p0, p1, p2, p3, p4, p5, p6, p7, p8, p9, p10, p11, p12, p13, p14, p15;
  CTC_LOAD(p0, 1)  CTC_LOAD(p1, 2)  CTC_LOAD(p2, 3)  CTC_LOAD(p3, 4)
  CTC_LOAD(p4, 5)  CTC_LOAD(p5, 6)  CTC_LOAD(p6, 7)  CTC_LOAD(p7, 8)
  CTC_LOAD(p8, 9)  CTC_LOAD(p9, 10) CTC_LOAD(p10, 11) CTC_LOAD(p11, 12)
  CTC_LOAD(p12, 13) CTC_LOAD(p13, 14) CTC_LOAD(p14, 15) CTC_LOAD(p15, 16)

#define CTC_STEP(P, T)                                                    \
  {                                                                       \
    asm volatile("s_waitcnt vmcnt(15)" ::: "memory");                     \
    __builtin_amdgcn_sched_barrier(0);                                    \
    f32x4 lp_ = P;                                                        \
    CTC_LOAD(P, (T) + 16)                                                 \
    float na3_ = dpp_shr1(a3, NEGV);                                      \
    float c0_ = lae2_2(a0, na3_);                                         \
    float c1_ = lae2_3(a1, a0, al1 ? na3_ : NEGV);                        \
    float c2_ = lae2_2(a2, a1);                                           \
    float c3_ = lae2_3(a3, a2, al3 ? a1 : NEGV);                          \
    if ((T) < ilen) {                                                     \
      a0 = c0_ + lp_[0]; a1 = c1_ + lp_[1];                               \
      a2 = c2_ + lp_[2]; a3 = c3_ + lp_[3];                               \
    }                                                                     \
  }

  // t runs 1..800 (50 groups of 16); t=800 update masked by (t<ilen), ilen<=800.
  // Tail loads reach row 816+15 inside batch b+1's region / final pad (allocated).
  for (int tb = 1; tb < CT + 1; tb += 16) {
    CTC_STEP(p0, tb + 0)   CTC_STEP(p1, tb + 1)   CTC_STEP(p2, tb + 2)
    CTC_STEP(p3, tb + 3)   CTC_STEP(p4, tb + 4)   CTC_STEP(p5, tb + 5)
    CTC_STEP(p6, tb + 6)   CTC_STEP(p7, tb + 7)   CTC_STEP(p8, tb + 8)
    CTC_STEP(p9, tb + 9)   CTC_STEP(p10, tb + 10) CTC_STEP(p11, tb + 11)
    CTC_STEP(p12, tb + 12) CTC_STEP(p13, tb + 13) CTC_STEP(p14, tb + 14)
    CTC_STEP(p15, tb + 15)
  }
  // drain: in-flight loads must land before their VGPRs can be reused below
  asm volatile("s_waitcnt vmcnt(0)" ::: "memory");
  __builtin_amdgcn_sched_barrier(0);

  __shared__ float sal[CSP];
  if (lane < CSP / 4) {
    sal[s0 + 0] = a0; sal[s0 + 1] = a1; sal[s0 + 2] = a2; sal[s0 + 3] = a3;
  }
  __syncthreads();
  if (lane == 0) {
    float last = sal[2 * ll];
    float prev = (ll > 0) ? sal[2 * ll - 1] : NEGV;
    float v = lae2_2(last, prev);                // log2 domain
    atomicAdd(out, -v * (LN2F / CBATCH));        // back to natural log
  }
#undef CTC_STEP
#undef CTC_LOAD
}

// ---------------- launch ----------------
extern "C" void kernel_launch(void* const* d_in, const int* in_sizes, int n_in,
                              void* d_out, int out_size, void* d_ws, size_t ws_size,
                              hipStream_t stream) {
  const float* hpad = (const float*)d_in[0];
  const float* W    = (const float*)d_in[1];
  const float* bias = (const float*)d_in[2];
  const int* labels = (const int*)d_in[3];
  const int* ilens  = (const int*)d_in[4];
  const int* llens  = (const int*)d_in[5];
  float* out = (float*)d_out;

  char* ws = (char*)d_ws;
  size_t off = 0;
  auto alloc = [&](size_t bytes) -> void* {
    void* p = ws + off;
    off = (off + bytes + 255) & ~(size_t)255;
    return p;
  };
  unsigned short* Abf = (unsigned short*)alloc((size_t)CM * CD * 2);        // 26.2 MB
  unsigned short* Wbf = (unsigned short*)alloc((size_t)CV * CD * 2);        //  1.0 MB
  unsigned short* logits = (unsigned short*)alloc((size_t)CM * CV * 2);     // 52.4 MB bf16
  float* lpg    = (float*)alloc((size_t)(CM + 64) * CSP * 4);               // 21.0 MB (+pad for prefetch overrun)

  hipMemsetAsync(d_out, 0, sizeof(float), stream);

  cvt_kernel<<<(CM * CD / 4 + 255) / 256, 256, 0, stream>>>(hpad, Abf, CM * CD / 4);
  cvt_kernel<<<(CV * CD / 4 + 255) / 256, 256, 0, stream>>>(W, Wbf, CV * CD / 4);
  gemm_kernel<<<dim3(CM / 128, CV / 128), 256, 0, stream>>>(Abf, Wbf, bias, logits);
  lse_gather_kernel<<<CM / 4, 256, 0, stream>>>(logits, labels, lpg);
  ctc_kernel<<<CBATCH, 64, 0, stream>>>(lpg, labels, ilens, llens, out);
}